// Round 8
// baseline (4236.315 us; speedup 1.0000x reference)
//
#include <hip/hip_runtime.h>
#include <hip/hip_bf16.h>

#define TSTEPS 512
#define BATCH  32
#define NIN    512
#define NH     1024
#define BNH    (BATCH * NH)   // 32768

typedef __attribute__((ext_vector_type(8))) short  short8v;
typedef __attribute__((ext_vector_type(4))) float  float4v;

__device__ __forceinline__ unsigned short f2bf(float f) {
  return __builtin_bit_cast(unsigned short, __float2bfloat16(f));
}
__device__ __forceinline__ float4v mfma16(short8v a, short8v b, float4v c) {
  return __builtin_amdgcn_mfma_f32_16x16x32_bf16(a, b, c, 0, 0, 0);
}

// bf16 fragment layout: element (b,k) at
//   (k>>5)*1024 + (b>>4)*512 + (((b&15)|(((k>>3)&3)<<4))<<3) + (k&7)
// -> wave A-fragment load (lane l, k-group kg, m-tile mt) is one 16B load at
//    base + kg*1024 + mt*512 + l*8 (contiguous per wave).
__device__ __forceinline__ int swzx(int b, int k) {
  return (k >> 5) * 1024 + (b >> 4) * 512 +
         (((b & 15) | (((k >> 3) & 3) << 4)) << 3) + (k & 7);
}

__device__ __forceinline__ short8v cvt8(float4 f0, float4 f1) {
  short8v r;
  r[0] = (short)f2bf(f0.x); r[1] = (short)f2bf(f0.y);
  r[2] = (short)f2bf(f0.z); r[3] = (short)f2bf(f0.w);
  r[4] = (short)f2bf(f1.x); r[5] = (short)f2bf(f1.y);
  r[6] = (short)f2bf(f1.z); r[7] = (short)f2bf(f1.w);
  return r;
}

// 8-k-group partial GEMM, bf16 fragment-layout source, PLAIN cached 16B loads.
__device__ __forceinline__ void kpartB(const ushort* __restrict__ base, int kgb,
                                       int lane, const short8v (&wreg)[8][2],
                                       float4v (&acc)[2][2]) {
  short8v f[2][8];
#pragma unroll
  for (int mt = 0; mt < 2; ++mt)
#pragma unroll
    for (int q = 0; q < 8; ++q)
      f[mt][q] = *(const short8v*)(base + (size_t)(kgb + q) * 1024 + mt * 512 + lane * 8);
#pragma unroll
  for (int q = 0; q < 8; ++q)
#pragma unroll
    for (int mt = 0; mt < 2; ++mt) {
      acc[mt][0] = mfma16(f[mt][q], wreg[q][0], acc[mt][0]);
      acc[mt][1] = mfma16(f[mt][q], wreg[q][1], acc[mt][1]);
    }
}

// 8-k-group partial GEMM, fp32 row-major source (row stride RS), plain loads.
template<int RS>
__device__ __forceinline__ void kpartF(const float* __restrict__ base, int kgb,
                                       int lane, const short8v (&wreg)[8][2],
                                       float4v (&acc)[2][2]) {
  const int r0 = lane & 15, koff = (lane >> 4) * 8;
  short8v f[2][8];
#pragma unroll
  for (int mt = 0; mt < 2; ++mt)
#pragma unroll
    for (int q = 0; q < 8; ++q) {
      const float* p = base + (size_t)(mt * 16 + r0) * RS + (kgb + q) * 32 + koff;
      f[mt][q] = cvt8(*(const float4*)p, *(const float4*)(p + 4));
    }
#pragma unroll
  for (int q = 0; q < 8; ++q)
#pragma unroll
    for (int mt = 0; mt < 2; ++mt) {
      acc[mt][0] = mfma16(f[mt][q], wreg[q][0], acc[mt][0]);
      acc[mt][1] = mfma16(f[mt][q], wreg[q][1], acc[mt][1]);
    }
}

// Poll 128 producer flags with one wave (2 flags/lane), scoped loads + backoff.
__device__ __forceinline__ void poll128(const int* __restrict__ flags, int base,
                                        int need, int lane) {
  if (need <= 0) return;
  const int* fa = flags + (size_t)(base + lane) * 16;
  const int* fb = flags + (size_t)(base + 64 + lane) * 16;
  for (;;) {
    int a = __hip_atomic_load(fa, __ATOMIC_RELAXED, __HIP_MEMORY_SCOPE_SYSTEM);
    int b = __hip_atomic_load(fb, __ATOMIC_RELAXED, __HIP_MEMORY_SCOPE_SYSTEM);
    if (__all((a >= need) && (b >= need))) break;
    __builtin_amdgcn_s_sleep(1);
  }
}

// Persistent kernel: 256 WGs x 512 threads (8 waves), 1 WG/CU.
// Layer by XCD residue: (wg&7)<4 -> layer0, else layer1. rank 0..127, 8 cols.
// Exchange protocol (correct by construction):
//   producers: sc0sc1 scoped stores (visible at LLC, L2 never dirty anywhere)
//              -> vmcnt(0) drain -> barrier -> tid0 scoped flag store.
//   consumers: dedicated poll wave (scoped flag reads) -> barrier -> PLAIN
//              cached loads. Addresses are write-once (full history): a line
//              can only enter L1/L2 after its producer wrote it, so plain
//              cached reads are never stale. Replays see identical values.
// L0 free-runs (no backpressure needed: full history, no slot reuse).
__global__ __launch_bounds__(512, 2)
void lstm_ch(const float* __restrict__ x,
             const float* __restrict__ h0_in,
             const float* __restrict__ c0_in,
             const float* __restrict__ W0, const float* __restrict__ b0_,
             const float* __restrict__ W1, const float* __restrict__ b1_,
             ushort* __restrict__ ring0,   // [TSTEPS+1][BNH] bf16, fragment layout
             int* __restrict__ flags,      // 256 producers x 16 ints (64B apart)
             float* __restrict__ out) {
  __shared__ float zl[8][32][36];          // per-wave z partials, 36-pad

  const int wg    = blockIdx.x;
  const int tid   = threadIdx.x;
  const int res   = wg & 7;
  const int layer = res >> 2;
  const int rank  = (wg >> 3) * 4 + (res & 3);
  const int j0    = rank * 8;
  const int K     = layer ? (2 * NH) : (NIN + NH);
  const float* W    = layer ? W1 : W0;
  const float* bias = layer ? b1_ : b0_;

  const int wv = tid >> 6, lane = tid & 63;
  const bool kactive = layer ? true : (wv < 6);

  // ---- preload this wave's weight K-slice into registers (once) ----
  short8v wreg[8][2];
  if (kactive) {
    const int wkbase = wv * 256;
#pragma unroll
    for (int q = 0; q < 8; ++q)
#pragma unroll
      for (int nt = 0; nt < 2; ++nt) {
        int n  = nt * 16 + (lane & 15);
        int gr = (n >> 3) * NH + j0 + (n & 7);
        int k  = wkbase + q * 32 + (lane >> 4) * 8;
        const float* p = W + (size_t)gr * K + k;
        wreg[q][nt] = cvt8(*(const float4*)p, *(const float4*)(p + 4));
      }
  } else {
#pragma unroll
    for (int q = 0; q < 8; ++q) { wreg[q][0] = short8v{}; wreg[q][1] = short8v{}; }
  }

  // zero my zl slice once (L0 waves 6-7 stay zero forever)
  for (int i = lane; i < 32 * 36; i += 64) (&zl[wv][0][0])[i] = 0.f;

  // epilogue state (threads 0..255): thread -> (batch bb, col jj)
  const int bb = tid >> 3, jj = tid & 7;
  float c = 0.f, bg0 = 0.f, bg1 = 0.f, bg2 = 0.f, bg3 = 0.f;
  if (tid < 256) {
    bg0 = bias[0 * NH + j0 + jj];
    bg1 = bias[1 * NH + j0 + jj];
    bg2 = bias[2 * NH + j0 + jj];
    bg3 = bias[3 * NH + j0 + jj];
    c   = c0_in[layer * BNH + bb * NH + j0 + jj];
  }

  __syncthreads();

  for (int it = 0; it < TSTEPS; ++it) {
    // ---- dependency pickup: dedicated poll waves, then barrier ----
    if (layer == 0) {
      if (wv == 2) poll128(flags, 0, it, lane);        // L0 peers done it-1
    } else {
      if (wv == 0) poll128(flags, 0, it + 1, lane);    // L0 done it (slot it+1)
      if (wv == 4) poll128(flags, 128, it, lane);      // L1 peers done it-1
    }
    __syncthreads();
    asm volatile("" ::: "memory");   // no hoisting loads above the gate

    // ---- partial GEMM (plain cached loads; L2 serves the duplication) ----
    float4v acc[2][2] = {{{0,0,0,0},{0,0,0,0}},{{0,0,0,0},{0,0,0,0}}};
    if (layer == 0) {
      if (wv < 2) {
        kpartF<NIN>(x + (size_t)it * BATCH * NIN, 8 * wv, lane, wreg, acc);
      } else if (wv < 6) {
        kpartB(ring0 + (size_t)it * BNH, 8 * (wv - 2), lane, wreg, acc);
      }
    } else {
      if (wv < 4) {
        kpartB(ring0 + (size_t)(it + 1) * BNH, 8 * wv, lane, wreg, acc);
      } else {
        const float* h1b = it ? (out + (size_t)(it - 1) * BNH) : (h0_in + BNH);
        kpartF<NH>(h1b, 8 * (wv - 4), lane, wreg, acc);
      }
    }

    if (kactive) {
#pragma unroll
      for (int mt = 0; mt < 2; ++mt)
#pragma unroll
        for (int nt = 0; nt < 2; ++nt)
#pragma unroll
          for (int r = 0; r < 4; ++r)
            zl[wv][mt * 16 + (lane >> 4) * 4 + r][nt * 16 + (lane & 15)] = acc[mt][nt][r];
    }
    __syncthreads();

    // ---- gates + state update + publish (scoped -> LLC) ----
    if (tid < 256) {
      float zg[4];
#pragma unroll
      for (int g = 0; g < 4; ++g) {
        float s = 0.f;
#pragma unroll
        for (int w = 0; w < 8; ++w) s += zl[w][bb][g * 8 + jj];
        zg[g] = s;
      }
      float g1 = 1.f / (1.f + __expf(-(zg[0] + bg0)));
      float g2 = 1.f / (1.f + __expf(-(zg[1] + bg1)));
      float g3 = 1.f / (1.f + __expf(-(zg[2] + bg2)));
      float o  = tanhf(zg[3] + bg3);
      c = c * g1 + o * g2;
      float h = tanhf(c) * g3;
      if (layer == 0) {
        __hip_atomic_store(&ring0[(size_t)(it + 1) * BNH + swzx(bb, j0 + jj)],
                           f2bf(h), __ATOMIC_RELAXED, __HIP_MEMORY_SCOPE_SYSTEM);
      } else {
        __hip_atomic_store(&out[(size_t)it * BNH + bb * NH + j0 + jj], h,
                           __ATOMIC_RELAXED, __HIP_MEMORY_SCOPE_SYSTEM);
      }
    }
    asm volatile("s_waitcnt vmcnt(0)" ::: "memory");   // drain scoped stores
    __syncthreads();
    if (tid == 0) {
      __hip_atomic_store(&flags[(size_t)(layer * 128 + rank) * 16], it + 1,
                         __ATOMIC_RELAXED, __HIP_MEMORY_SCOPE_SYSTEM);
    }
  }
}

// prep: ring0 slot 0 (h0 layer-0 init, fragment layout, scoped), zero flags,
// copy (h0,c0) passthrough tail of the output.
__global__ void prep(const float* __restrict__ h0_in, const float* __restrict__ c0_in,
                     ushort* __restrict__ ring0, int* __restrict__ flags,
                     float* __restrict__ out) {
  int i = blockIdx.x * blockDim.x + threadIdx.x;   // 0 .. 2*BNH-1
  if (i < BNH) {
    int b = i >> 10, j = i & 1023;
    __hip_atomic_store(&ring0[swzx(b, j)], f2bf(h0_in[i]),
                       __ATOMIC_RELAXED, __HIP_MEMORY_SCOPE_SYSTEM);
  }
  if (i < 256 * 16) {
    __hip_atomic_store(&flags[i], 0, __ATOMIC_RELAXED, __HIP_MEMORY_SCOPE_SYSTEM);
  }
  const size_t TB = (size_t)TSTEPS * BNH;
  out[TB + i]           = h0_in[i];
  out[TB + 2 * BNH + i] = c0_in[i];
}

extern "C" void kernel_launch(void* const* d_in, const int* in_sizes, int n_in,
                              void* d_out, int out_size, void* d_ws, size_t ws_size,
                              hipStream_t stream) {
  const float* x  = (const float*)d_in[0];
  const float* h0 = (const float*)d_in[1];
  const float* c0 = (const float*)d_in[2];
  const float* W0 = (const float*)d_in[3];
  const float* b0 = (const float*)d_in[4];
  const float* W1 = (const float*)d_in[5];
  const float* b1 = (const float*)d_in[6];
  float* out = (float*)d_out;

  // ws: ring0 full history 33,619,968 B + flags 16 KiB (<= proven ws_size)
  ushort* ring0 = (ushort*)d_ws;
  int*    flags = (int*)((char*)d_ws + (size_t)(TSTEPS + 1) * BNH * 2);

  prep<<<dim3(256), dim3(256), 0, stream>>>(h0, c0, ring0, flags, out);

  void* args[] = {(void*)&x, (void*)&h0, (void*)&c0, (void*)&W0, (void*)&b0,
                  (void*)&W1, (void*)&b1, (void*)&ring0, (void*)&flags, (void*)&out};
  (void)hipLaunchCooperativeKernel((const void*)lstm_ch, dim3(256), dim3(512),
                                   args, 0, stream);
}